// Round 17
// baseline (154.941 us; speedup 1.0000x reference)
//
#include <hip/hip_runtime.h>

#define TT 1024
#define KK 16
#define HH 20
#define NCELL 1024

typedef _Float16 f16;
typedef f16 f16x2 __attribute__((ext_vector_type(2)));
typedef __fp16 fp16x2_raw __attribute__((ext_vector_type(2)));  // cvt_pkrtz return type

#define LOG2E 1.4426950408889634f

__device__ __forceinline__ float fdot2(f16x2 a, f16x2 b, float c) {
    // v_dot2_f32_f16: a.x*b.x + a.y*b.y + c, f32 accumulate.
    return __builtin_amdgcn_fdot2(a, b, c, false);
}
// Gate dot with the h pair consumed DIRECTLY from an SGPR (VOP3P allows one
// scalar source). Readlane results live in SGPRs; the builtin's vector-typed
// operand can force a v_mov per pair (10/step). This keeps them scalar.
__device__ __forceinline__ float fdot2_sv(f16x2 w_v, unsigned h_s, float c) {
    float d;
    asm("v_dot2_f32_f16 %0, %1, %2, %3"
        : "=v"(d) : "v"(w_v), "s"(h_s), "v"(c));
    return d;
}
__device__ __forceinline__ float fast_rcp(float x) {
    return __builtin_amdgcn_rcpf(x);
}
// sigmoid in exp2 domain (x pre-scaled by log2e): rcp(1 + 2^-x).
__device__ __forceinline__ float sigm2(float x2) {
    return fast_rcp(1.0f + __builtin_amdgcn_exp2f(-x2));
}
// tanh of a TRUE-domain value.
__device__ __forceinline__ float tanh_fast(float x) {
    float e = __builtin_amdgcn_exp2f(x * (2.0f * LOG2E));
    return 1.0f - 2.0f * fast_rcp(e + 1.0f);
}
__device__ __forceinline__ float bcast(float v, int srclane) {
    return __int_as_float(__builtin_amdgcn_readlane(__float_as_int(v), srclane));
}
__device__ __forceinline__ unsigned bcast_u(unsigned v, int srclane) {
    return (unsigned)__builtin_amdgcn_readlane((int)v, srclane);
}

// v_permlane32_swap_b32 a,b with a=b=v: a = v's low-half value in ALL lanes,
// b = v's high-half value in ALL lanes.
__device__ __forceinline__ void half_bcast(float v, float& from_lo, float& from_hi) {
    float a = v, b = v;
    asm("v_permlane32_swap_b32 %0, %1" : "+v"(a), "+v"(b));
    from_lo = a; from_hi = b;
}

// R16 + SGPR-direct gate dots (R16 post-mortem: issue-bound at 74% VALUBusy,
// ~262cy issue / ~93cy stall per 355cy step; MAC path at the 2-MAC/instr
// floor; memory fully hidden; 2-wave consolidation analytically worse
// (2x262 > 355). Last slack: 10 possible v_movs repacking readlane SGPRs
// into VGPRs for the builtin dot — eliminated via inline-asm "s" operand,
// the same trick R8 proved on pk_fma.)
//
// Structure: ONE cell per wave, gates split across halves (lanes 0..31:
// rows i,f of unit j=min(lane&31,19); lanes 32..63: rows g,o); f16 weights
// pre-scaled by log2e (g-row 2x); dot2 in two 5-deep chains; h broadcast =
// DPP-xor1 + cvt_pkrtz + 10 readlanes of packed pairs; recombine via
// v_permlane32_swap_b32; exp2-domain activations; input trace LDS-staged
// (f16-packed) with padded tail + group-top refill.
// waves_per_eu(1,1): truthful (1024 blocks / 256 CU = 1 wave/SIMD).
__global__ __launch_bounds__(64)
__attribute__((amdgpu_waves_per_eu(1, 1)))
void lstm_kernel(
    const float* __restrict__ inp,    // [B][T][K][3]
    const float* __restrict__ W_ih,   // [K][80][3]
    const float* __restrict__ W_hh,   // [K][80][20]
    const float* __restrict__ b_ih,   // [K][80]
    const float* __restrict__ b_hh,   // [K][80]
    const float* __restrict__ w,      // [K*B+1]
    const float* __restrict__ conv_w, // [21]
    const float* __restrict__ conv_b, // [1]
    float* __restrict__ y_ws)         // [1024] pre-softmax y for rows 1..1024
{
    __shared__ unsigned long long xs[TT + 4];  // lo32=(x0,x1) f16x2, hi32=(x2,1)

    const int lane = threadIdx.x;
    const int cell = blockIdx.x;           // 0..1023
    const int k = cell >> 6;
    const int b = cell & 63;
    const int half = lane >> 5;            // 0: rows i,f   1: rows g,o
    const int jj = lane & 31;
    const int j = (jj < HH) ? jj : (HH - 1);

    // ---- Stage input trace for this cell into LDS (once; tail padded) ----
    {
        const float* xbg = inp + (b * TT * KK + k) * 3;
        for (int i = lane; i < TT + 4; i += 64) {
            const int t = (i < TT) ? i : (TT - 1);
            const float* q = xbg + t * (KK * 3);
            const f16x2 lo = f16x2{(f16)q[0], (f16)q[1]};
            const f16x2 hi = f16x2{(f16)q[2], (f16)1.0f};
            xs[i] = ((unsigned long long)__builtin_bit_cast(unsigned, hi) << 32)
                  | __builtin_bit_cast(unsigned, lo);
        }
    }

    // Per-lane weights: row A = (half?g:i), row B = (half?o:f), f16 pre-scaled.
    f16x2 WhA[10], WhB[10];
    f16x2 WxA01, WxA2b, WxB01, WxB2b;   // xproj weights; bias folded into *2b
    {
        const int rA = k * 80 + (half * 2) * HH + j;
        const int rB = rA + HH;
        const float scaleA = LOG2E * (half ? 2.0f : 1.0f);  // g-row: sigma(2x)
        const float scaleB = LOG2E;
        #pragma unroll
        for (int m = 0; m < 10; ++m) {
            WhA[m] = f16x2{(f16)(W_hh[rA * HH + 2 * m] * scaleA),
                           (f16)(W_hh[rA * HH + 2 * m + 1] * scaleA)};
            WhB[m] = f16x2{(f16)(W_hh[rB * HH + 2 * m] * scaleB),
                           (f16)(W_hh[rB * HH + 2 * m + 1] * scaleB)};
        }
        WxA01 = f16x2{(f16)(W_ih[rA * 3 + 0] * scaleA), (f16)(W_ih[rA * 3 + 1] * scaleA)};
        WxB01 = f16x2{(f16)(W_ih[rB * 3 + 0] * scaleB), (f16)(W_ih[rB * 3 + 1] * scaleB)};
        WxA2b = f16x2{(f16)(W_ih[rA * 3 + 2] * scaleA),
                      (f16)((b_ih[rA] + b_hh[rA]) * scaleA)};
        WxB2b = f16x2{(f16)(W_ih[rB * 3 + 2] * scaleB),
                      (f16)((b_ih[rB] + b_hh[rB]) * scaleB)};
    }
    // A-row post-activation affine: half0 identity; half1 tanh = 2*sigma(2x)-1.
    const float mA = half ? 2.0f : 1.0f;
    const float bA = half ? -1.0f : 0.0f;

    float h_own = 0.0f, c_own = 0.0f;

    __syncthreads();   // staging visible

    auto step = [&](const unsigned long long xq) {
        // 1) h-pack: neighbor f32 via DPP xor1, ONE cvt_pkrtz -> (h2m, h2m+1);
        //    10 readlanes -> packed pairs, kept in SGPRs end-to-end.
        const unsigned hb32 = __float_as_uint(h_own);
        const unsigned nb32 =
            (unsigned)__builtin_amdgcn_mov_dpp((int)hb32, 0xB1, 0xF, 0xF, true);
        const fp16x2_raw hpk_raw =
            __builtin_amdgcn_cvt_pkrtz(h_own, __uint_as_float(nb32));
        const unsigned packed = __builtin_bit_cast(unsigned, hpk_raw);
        unsigned hs[10];
        #pragma unroll
        for (int m = 0; m < 10; ++m) hs[m] = bcast_u(packed, 2 * m);

        const f16x2 xp01 = __builtin_bit_cast(f16x2, (unsigned)xq);
        const f16x2 xp2b = __builtin_bit_cast(f16x2, (unsigned)(xq >> 32));
        // 2) x-projection (2 dot2 per row, bias folded into the (x2,1) dot)
        const float eA = fdot2(WxA01, xp01, fdot2(WxA2b, xp2b, 0.0f));
        const float eB = fdot2(WxB01, xp01, fdot2(WxB2b, xp2b, 0.0f));
        // 3) gate dots: 10 dot2 per row, two 5-deep chains, h pair from SGPR
        float pA0 = eA, pA1 = 0.f, pB0 = eB, pB1 = 0.f;
        #pragma unroll
        for (int m = 0; m < 5; ++m) {
            pA0 = fdot2_sv(WhA[m], hs[m], pA0);
            pB0 = fdot2_sv(WhB[m], hs[m], pB0);
            pA1 = fdot2_sv(WhA[m + 5], hs[m + 5], pA1);
            pB1 = fdot2_sv(WhB[m + 5], hs[m + 5], pB1);
        }
        const float gA = pA0 + pA1;     // half0: i-pre   half1: g-pre (scaled)
        const float gB = pB0 + pB1;     // half0: f-pre   half1: o-pre (scaled)
        // 4) activations (exp2 domain)
        const float uA = sigm2(gA);
        const float actA = uA * mA + bA;       // sigma(i) or tanh(g)
        const float actB = sigm2(gB);          // sigma(f) or sigma(o)
        // 5) cross-half exchange: all lanes get sI, tG, sF, sO for unit jj
        float sI, tG, sF, sO;
        half_bcast(actA, sI, tG);
        half_bcast(actB, sF, sO);
        // 6) state update (h_own valid in lanes 0..19, shadowed in 32..51)
        c_own = sF * c_own + sI * tG;
        h_own = sO * tanh_fast(c_own);
    };

    // 4-deep rotation; refills for the NEXT group issued at group top with
    // immediate offsets, consumed as register renames at group end.
    unsigned long long xq0 = xs[0], xq1 = xs[1], xq2 = xs[2], xq3 = xs[3];
    for (int tb = 0; tb < TT; tb += 4) {
        const unsigned long long xn0 = xs[tb + 4];
        const unsigned long long xn1 = xs[tb + 5];
        const unsigned long long xn2 = xs[tb + 6];
        const unsigned long long xn3 = xs[tb + 7];
        step(xq0);
        step(xq1);
        step(xq2);
        step(xq3);
        xq0 = xn0; xq1 = xn1; xq2 = xn2; xq3 = xn3;
    }

    // Epilogue: final h via readlane (f32), y = tanh(feat . conv_w + conv_b)
    float acc = conv_b[0];
    #pragma unroll
    for (int hh = 0; hh < HH; ++hh) acc += conv_w[hh] * bcast(h_own, hh);
    acc += conv_w[HH] * w[1 + cell];
    if (lane == 0) y_ws[cell] = tanh_fast(acc);
}

// Softmax over [1, y_0 .. y_1023] -> out[1025]
__global__ __launch_bounds__(256) void softmax_kernel(
    const float* __restrict__ y_ws, float* __restrict__ out)
{
    __shared__ float red[4];
    const int tid = threadIdx.x;
    float vals[5];
    float local = 0.0f;
    #pragma unroll
    for (int it = 0; it < 5; ++it) {
        const int idx = tid + it * 256;
        if (idx < NCELL + 1) {
            const float y = (idx == 0) ? 1.0f : y_ws[idx - 1];
            const float e = __expf(y);
            vals[it] = e;
            local += e;
        } else {
            vals[it] = 0.0f;
        }
    }
    #pragma unroll
    for (int off = 32; off > 0; off >>= 1) local += __shfl_down(local, off, 64);
    if ((tid & 63) == 0) red[tid >> 6] = local;
    __syncthreads();
    const float total = red[0] + red[1] + red[2] + red[3];
    const float inv = 1.0f / total;
    #pragma unroll
    for (int it = 0; it < 5; ++it) {
        const int idx = tid + it * 256;
        if (idx < NCELL + 1) out[idx] = vals[it] * inv;
    }
}

extern "C" void kernel_launch(void* const* d_in, const int* in_sizes, int n_in,
                              void* d_out, int out_size, void* d_ws, size_t ws_size,
                              hipStream_t stream) {
    const float* inp    = (const float*)d_in[0];
    const float* w      = (const float*)d_in[1];
    const float* W_ih   = (const float*)d_in[2];
    const float* W_hh   = (const float*)d_in[3];
    const float* b_ih   = (const float*)d_in[4];
    const float* b_hh   = (const float*)d_in[5];
    const float* conv_w = (const float*)d_in[6];
    const float* conv_b = (const float*)d_in[7];
    float* out  = (float*)d_out;
    float* y_ws = (float*)d_ws;

    lstm_kernel<<<NCELL, 64, 0, stream>>>(inp, W_ih, W_hh, b_ih, b_hh, w,
                                          conv_w, conv_b, y_ws);
    softmax_kernel<<<1, 256, 0, stream>>>(y_ws, out);
}

// Round 18
// 151.105 us; speedup vs baseline: 1.0254x; 1.0254x over previous
//
#include <hip/hip_runtime.h>

#define TT 1024
#define KK 16
#define HH 20
#define NCELL 1024

typedef _Float16 f16;
typedef f16 f16x2 __attribute__((ext_vector_type(2)));
typedef __fp16 fp16x2_raw __attribute__((ext_vector_type(2)));  // cvt_pkrtz return type

#define LOG2E 1.4426950408889634f

__device__ __forceinline__ float fdot2(f16x2 a, f16x2 b, float c) {
    // v_dot2_f32_f16: a.x*b.x + a.y*b.y + c, f32 accumulate.
    return __builtin_amdgcn_fdot2(a, b, c, false);
}
__device__ __forceinline__ float fast_rcp(float x) {
    return __builtin_amdgcn_rcpf(x);
}
// sigmoid in exp2 domain (x pre-scaled by log2e): rcp(1 + 2^-x).
__device__ __forceinline__ float sigm2(float x2) {
    return fast_rcp(1.0f + __builtin_amdgcn_exp2f(-x2));
}
// tanh of a TRUE-domain value.
__device__ __forceinline__ float tanh_fast(float x) {
    float e = __builtin_amdgcn_exp2f(x * (2.0f * LOG2E));
    return 1.0f - 2.0f * fast_rcp(e + 1.0f);
}
__device__ __forceinline__ float bcast(float v, int srclane) {
    return __int_as_float(__builtin_amdgcn_readlane(__float_as_int(v), srclane));
}
__device__ __forceinline__ unsigned bcast_u(unsigned v, int srclane) {
    return (unsigned)__builtin_amdgcn_readlane((int)v, srclane);
}

// v_permlane32_swap_b32 a,b with a=b=v: a = v's low-half value in ALL lanes,
// b = v's high-half value in ALL lanes.
__device__ __forceinline__ void half_bcast(float v, float& from_lo, float& from_hi) {
    float a = v, b = v;
    asm("v_permlane32_swap_b32 %0, %1" : "+v"(a), "+v"(b));
    from_lo = a; from_hi = b;
}

// R16 verbatim — best verified state (151.4us). R17's SGPR-direct dot was
// flat-to-negative: the compiler already folds readlane SGPRs into VOP3P
// dots; the asm wrapper only hurt scheduling. Structural floor:
//   355 cy/step = ~260 cy issue (24 dot2 at the 2-MAC/instr floor +
//   10 readlane h-broadcast + 6 quarter-rate trans + pack/exchange/update)
//   + ~95 cy exposed chain latency; 1 wave/SIMD (1024 serial chains on 1024
//   SIMDs), zero memory on the critical path (R14), consolidation
//   analytically negative (2x issue > step).
//
// Structure: ONE cell per wave, gates split across halves (lanes 0..31:
// rows i,f of unit j=min(lane&31,19); lanes 32..63: rows g,o); f16 weights
// pre-scaled by log2e (g-row 2x); dot2 in two 5-deep chains; h broadcast =
// DPP-xor1 + cvt_pkrtz + 10 readlanes of packed pairs; recombine via
// v_permlane32_swap_b32; exp2-domain activations; input trace LDS-staged
// (f16-packed) with padded tail + group-top refill.
// waves_per_eu(1,1): truthful (1024 blocks / 256 CU = 1 wave/SIMD).
__global__ __launch_bounds__(64)
__attribute__((amdgpu_waves_per_eu(1, 1)))
void lstm_kernel(
    const float* __restrict__ inp,    // [B][T][K][3]
    const float* __restrict__ W_ih,   // [K][80][3]
    const float* __restrict__ W_hh,   // [K][80][20]
    const float* __restrict__ b_ih,   // [K][80]
    const float* __restrict__ b_hh,   // [K][80]
    const float* __restrict__ w,      // [K*B+1]
    const float* __restrict__ conv_w, // [21]
    const float* __restrict__ conv_b, // [1]
    float* __restrict__ y_ws)         // [1024] pre-softmax y for rows 1..1024
{
    __shared__ unsigned long long xs[TT + 4];  // lo32=(x0,x1) f16x2, hi32=(x2,1)

    const int lane = threadIdx.x;
    const int cell = blockIdx.x;           // 0..1023
    const int k = cell >> 6;
    const int b = cell & 63;
    const int half = lane >> 5;            // 0: rows i,f   1: rows g,o
    const int jj = lane & 31;
    const int j = (jj < HH) ? jj : (HH - 1);

    // ---- Stage input trace for this cell into LDS (once; tail padded) ----
    {
        const float* xbg = inp + (b * TT * KK + k) * 3;
        for (int i = lane; i < TT + 4; i += 64) {
            const int t = (i < TT) ? i : (TT - 1);
            const float* q = xbg + t * (KK * 3);
            const f16x2 lo = f16x2{(f16)q[0], (f16)q[1]};
            const f16x2 hi = f16x2{(f16)q[2], (f16)1.0f};
            xs[i] = ((unsigned long long)__builtin_bit_cast(unsigned, hi) << 32)
                  | __builtin_bit_cast(unsigned, lo);
        }
    }

    // Per-lane weights: row A = (half?g:i), row B = (half?o:f), f16 pre-scaled.
    f16x2 WhA[10], WhB[10];
    f16x2 WxA01, WxA2b, WxB01, WxB2b;   // xproj weights; bias folded into *2b
    {
        const int rA = k * 80 + (half * 2) * HH + j;
        const int rB = rA + HH;
        const float scaleA = LOG2E * (half ? 2.0f : 1.0f);  // g-row: sigma(2x)
        const float scaleB = LOG2E;
        #pragma unroll
        for (int m = 0; m < 10; ++m) {
            WhA[m] = f16x2{(f16)(W_hh[rA * HH + 2 * m] * scaleA),
                           (f16)(W_hh[rA * HH + 2 * m + 1] * scaleA)};
            WhB[m] = f16x2{(f16)(W_hh[rB * HH + 2 * m] * scaleB),
                           (f16)(W_hh[rB * HH + 2 * m + 1] * scaleB)};
        }
        WxA01 = f16x2{(f16)(W_ih[rA * 3 + 0] * scaleA), (f16)(W_ih[rA * 3 + 1] * scaleA)};
        WxB01 = f16x2{(f16)(W_ih[rB * 3 + 0] * scaleB), (f16)(W_ih[rB * 3 + 1] * scaleB)};
        WxA2b = f16x2{(f16)(W_ih[rA * 3 + 2] * scaleA),
                      (f16)((b_ih[rA] + b_hh[rA]) * scaleA)};
        WxB2b = f16x2{(f16)(W_ih[rB * 3 + 2] * scaleB),
                      (f16)((b_ih[rB] + b_hh[rB]) * scaleB)};
    }
    // A-row post-activation affine: half0 identity; half1 tanh = 2*sigma(2x)-1.
    const float mA = half ? 2.0f : 1.0f;
    const float bA = half ? -1.0f : 0.0f;

    float h_own = 0.0f, c_own = 0.0f;

    __syncthreads();   // staging visible

    auto step = [&](const unsigned long long xq) {
        // 1) h-pack: neighbor f32 via DPP xor1, ONE cvt_pkrtz -> (h2m, h2m+1);
        //    10 readlanes of packed f16x2 -> wave-uniform operands for dot2.
        const unsigned hb32 = __float_as_uint(h_own);
        const unsigned nb32 =
            (unsigned)__builtin_amdgcn_mov_dpp((int)hb32, 0xB1, 0xF, 0xF, true);
        const fp16x2_raw hpk_raw =
            __builtin_amdgcn_cvt_pkrtz(h_own, __uint_as_float(nb32));
        const unsigned packed = __builtin_bit_cast(unsigned, hpk_raw);
        f16x2 hp[10];
        #pragma unroll
        for (int m = 0; m < 10; ++m)
            hp[m] = __builtin_bit_cast(f16x2, bcast_u(packed, 2 * m));

        const f16x2 xp01 = __builtin_bit_cast(f16x2, (unsigned)xq);
        const f16x2 xp2b = __builtin_bit_cast(f16x2, (unsigned)(xq >> 32));
        // 2) x-projection (2 dot2 per row, bias folded into the (x2,1) dot)
        const float eA = fdot2(WxA01, xp01, fdot2(WxA2b, xp2b, 0.0f));
        const float eB = fdot2(WxB01, xp01, fdot2(WxB2b, xp2b, 0.0f));
        // 3) gate dots: 10 dot2 per row, two 5-deep chains
        float pA0 = eA, pA1 = 0.f, pB0 = eB, pB1 = 0.f;
        #pragma unroll
        for (int m = 0; m < 5; ++m) {
            pA0 = fdot2(WhA[m], hp[m], pA0);
            pB0 = fdot2(WhB[m], hp[m], pB0);
            pA1 = fdot2(WhA[m + 5], hp[m + 5], pA1);
            pB1 = fdot2(WhB[m + 5], hp[m + 5], pB1);
        }
        const float gA = pA0 + pA1;     // half0: i-pre   half1: g-pre (scaled)
        const float gB = pB0 + pB1;     // half0: f-pre   half1: o-pre (scaled)
        // 4) activations (exp2 domain)
        const float uA = sigm2(gA);
        const float actA = uA * mA + bA;       // sigma(i) or tanh(g)
        const float actB = sigm2(gB);          // sigma(f) or sigma(o)
        // 5) cross-half exchange: all lanes get sI, tG, sF, sO for unit jj
        float sI, tG, sF, sO;
        half_bcast(actA, sI, tG);
        half_bcast(actB, sF, sO);
        // 6) state update (h_own valid in lanes 0..19, shadowed in 32..51)
        c_own = sF * c_own + sI * tG;
        h_own = sO * tanh_fast(c_own);
    };

    // 4-deep rotation; refills for the NEXT group issued at group top with
    // immediate offsets, consumed as register renames at group end.
    unsigned long long xq0 = xs[0], xq1 = xs[1], xq2 = xs[2], xq3 = xs[3];
    for (int tb = 0; tb < TT; tb += 4) {
        const unsigned long long xn0 = xs[tb + 4];
        const unsigned long long xn1 = xs[tb + 5];
        const unsigned long long xn2 = xs[tb + 6];
        const unsigned long long xn3 = xs[tb + 7];
        step(xq0);
        step(xq1);
        step(xq2);
        step(xq3);
        xq0 = xn0; xq1 = xn1; xq2 = xn2; xq3 = xn3;
    }

    // Epilogue: final h via readlane (f32), y = tanh(feat . conv_w + conv_b)
    float acc = conv_b[0];
    #pragma unroll
    for (int hh = 0; hh < HH; ++hh) acc += conv_w[hh] * bcast(h_own, hh);
    acc += conv_w[HH] * w[1 + cell];
    if (lane == 0) y_ws[cell] = tanh_fast(acc);
}

// Softmax over [1, y_0 .. y_1023] -> out[1025]
__global__ __launch_bounds__(256) void softmax_kernel(
    const float* __restrict__ y_ws, float* __restrict__ out)
{
    __shared__ float red[4];
    const int tid = threadIdx.x;
    float vals[5];
    float local = 0.0f;
    #pragma unroll
    for (int it = 0; it < 5; ++it) {
        const int idx = tid + it * 256;
        if (idx < NCELL + 1) {
            const float y = (idx == 0) ? 1.0f : y_ws[idx - 1];
            const float e = __expf(y);
            vals[it] = e;
            local += e;
        } else {
            vals[it] = 0.0f;
        }
    }
    #pragma unroll
    for (int off = 32; off > 0; off >>= 1) local += __shfl_down(local, off, 64);
    if ((tid & 63) == 0) red[tid >> 6] = local;
    __syncthreads();
    const float total = red[0] + red[1] + red[2] + red[3];
    const float inv = 1.0f / total;
    #pragma unroll
    for (int it = 0; it < 5; ++it) {
        const int idx = tid + it * 256;
        if (idx < NCELL + 1) out[idx] = vals[it] * inv;
    }
}

extern "C" void kernel_launch(void* const* d_in, const int* in_sizes, int n_in,
                              void* d_out, int out_size, void* d_ws, size_t ws_size,
                              hipStream_t stream) {
    const float* inp    = (const float*)d_in[0];
    const float* w      = (const float*)d_in[1];
    const float* W_ih   = (const float*)d_in[2];
    const float* W_hh   = (const float*)d_in[3];
    const float* b_ih   = (const float*)d_in[4];
    const float* b_hh   = (const float*)d_in[5];
    const float* conv_w = (const float*)d_in[6];
    const float* conv_b = (const float*)d_in[7];
    float* out  = (float*)d_out;
    float* y_ws = (float*)d_ws;

    lstm_kernel<<<NCELL, 64, 0, stream>>>(inp, W_ih, W_hh, b_ih, b_hh, w,
                                          conv_w, conv_b, y_ws);
    softmax_kernel<<<1, 256, 0, stream>>>(y_ws, out);
}